// Round 1
// baseline (174.600 us; speedup 1.0000x reference)
//
#include <hip/hip_runtime.h>

// EvolutionModelTorch — Jukes-Cantor pair-likelihood.
// Analytic JC: T(t) = 1/4 + 3/4 e^{-4t/3} on diag, 1/4 - 1/4 e^{-4t/3} off-diag.
// y[c] = sum_v x[v] T[v][c] = e * x[c] + 0.25*(1-e)*S,  S = sum_v x[v].
// joint[b,m,c] = y1[c] * y2[c] * p,  p = exp((log 10 - 10(t1+t2))/8192)  (p folded into y1 coeffs)
// log_p[b] = sum_m log(0.25 * sum_c joint[b,m,c])

constexpr int SEQ_LEN = 8192;
constexpr int BATCH   = 512;
constexpr int TPB     = 256;
constexpr int CHUNKS  = 8;                       // blocks per batch
constexpr int SPT     = SEQ_LEN / (CHUNKS * TPB); // sites per thread = 4

__global__ __launch_bounds__(TPB) void evo_main(
    const float* __restrict__ f1, const float* __restrict__ br1,
    const float* __restrict__ f2, const float* __restrict__ br2,
    float* __restrict__ joint, float* __restrict__ logp)
{
    const int blk   = blockIdx.x;
    const int b     = blk >> 3;              // / CHUNKS
    const int chunk = blk & (CHUNKS - 1);

    const float t1 = br1[b];
    const float t2 = br2[b];
    const float e1 = __expf(-(4.0f / 3.0f) * t1);
    const float e2 = __expf(-(4.0f / 3.0f) * t2);
    // prior factor spread over sites; log(10) = 2.302585092994046
    const float p  = __expf((2.3025850929940457f - 10.0f * (t1 + t2)) * (1.0f / (float)SEQ_LEN));
    const float pe1 = p * e1;                      // fold p into feature-1 affine map
    const float pc1 = p * 0.25f * (1.0f - e1);
    const float c2  = 0.25f * (1.0f - e2);

    const size_t base = (size_t)b * SEQ_LEN + (size_t)chunk * (TPB * SPT);
    const float4* __restrict__ F1 = (const float4*)f1 + base;
    const float4* __restrict__ F2 = (const float4*)f2 + base;
    float4* __restrict__ J = (float4*)joint + base;

    float lsum = 0.0f;
#pragma unroll
    for (int k = 0; k < SPT; ++k) {
        const int i = k * TPB + (int)threadIdx.x;  // coalesced: lane i -> float4 i
        const float4 x = F1[i];
        const float4 y = F2[i];
        const float a1 = pc1 * ((x.x + x.y) + (x.z + x.w));
        const float a2 = c2  * ((y.x + y.y) + (y.z + y.w));
        float4 o;
        o.x = fmaf(pe1, x.x, a1) * fmaf(e2, y.x, a2);
        o.y = fmaf(pe1, x.y, a1) * fmaf(e2, y.y, a2);
        o.z = fmaf(pe1, x.z, a1) * fmaf(e2, y.z, a2);
        o.w = fmaf(pe1, x.w, a1) * fmaf(e2, y.w, a2);
        J[i] = o;
        lsum += __logf(0.25f * ((o.x + o.y) + (o.z + o.w)));
    }

    // wave64 butterfly-free down-reduce
#pragma unroll
    for (int off = 32; off > 0; off >>= 1)
        lsum += __shfl_down(lsum, off, 64);

    __shared__ float wsum[TPB / 64];
    const int lane = threadIdx.x & 63;
    const int wid  = threadIdx.x >> 6;
    if (lane == 0) wsum[wid] = lsum;
    __syncthreads();
    if (threadIdx.x == 0) {
        const float s = (wsum[0] + wsum[1]) + (wsum[2] + wsum[3]);
        atomicAdd(&logp[b], s);   // 8 atomics per batch, device scope
    }
}

extern "C" void kernel_launch(void* const* d_in, const int* in_sizes, int n_in,
                              void* d_out, int out_size, void* d_ws, size_t ws_size,
                              hipStream_t stream) {
    const float* f1  = (const float*)d_in[0];
    const float* br1 = (const float*)d_in[1];
    const float* f2  = (const float*)d_in[2];
    const float* br2 = (const float*)d_in[3];
    float* joint = (float*)d_out;
    float* logp  = joint + (size_t)BATCH * SEQ_LEN * 4;

    // log_p region is poisoned 0xAA before every timed call -> zero it (graph-legal memset node)
    hipMemsetAsync(logp, 0, BATCH * sizeof(float), stream);

    evo_main<<<BATCH * CHUNKS, TPB, 0, stream>>>(f1, br1, f2, br2, joint, logp);
}